// Round 12
// baseline (872.945 us; speedup 1.0000x reference)
//
#include <hip/hip_runtime.h>
#include <hip/hip_bf16.h>
#include <stdint.h>

// Problem constants (QuantizedLinear_15985868276124)
#define IN_F   4096
#define OUT_F  11008
#define M_TOK  8192                  // 4 * 2048 tokens
#define NGRP   (OUT_F * (IN_F / 8)) // 5,636,096 groups of 8 weights

typedef __attribute__((ext_vector_type(8))) short short8;
typedef __attribute__((ext_vector_type(4))) float f32x4;

// ---------- helpers ----------

__device__ __forceinline__ unsigned short bf16_rne(float f) {
    union { float f; uint32_t u; } v; v.f = f;
    uint32_t r = v.u + 0x7FFFu + ((v.u >> 16) & 1u); // round-to-nearest-even
    return (unsigned short)(r >> 16);
}

// ---------- kernel 1: dequantize W -> bf16 [OUT_F][IN_F] ----------
__global__ __launch_bounds__(256) void k_dequant(
        const int* __restrict__ codes,
        const float* __restrict__ codebooks,
        const float* __restrict__ scales,
        unsigned short* __restrict__ Wq) {
    __shared__ float cb[4096]; // [2][256][8]
    int tid = threadIdx.x;
    const float4* cbg = (const float4*)codebooks;
    float4* cbl = (float4*)cb;
#pragma unroll
    for (int i = 0; i < 4; ++i) cbl[tid + i * 256] = cbg[tid + i * 256];
    __syncthreads();

    int gidx = blockIdx.x * 256 + tid;      // group index in [0, NGRP)
    int o = gidx >> 9;                      // / 512
    float s = scales[o];
    int2 c = ((const int2*)codes)[gidx];

    const float4* e0 = (const float4*)&cb[c.x * 8];
    const float4* e1 = (const float4*)&cb[2048 + c.y * 8];
    float4 a0 = e0[0], a1 = e0[1];
    float4 b0 = e1[0], b1 = e1[1];

    float r[8];
    r[0] = (a0.x + b0.x) * s; r[1] = (a0.y + b0.y) * s;
    r[2] = (a0.z + b0.z) * s; r[3] = (a0.w + b0.w) * s;
    r[4] = (a1.x + b1.x) * s; r[5] = (a1.y + b1.y) * s;
    r[6] = (a1.z + b1.z) * s; r[7] = (a1.w + b1.w) * s;

    uint4 pk;
    pk.x = (uint32_t)bf16_rne(r[0]) | ((uint32_t)bf16_rne(r[1]) << 16);
    pk.y = (uint32_t)bf16_rne(r[2]) | ((uint32_t)bf16_rne(r[3]) << 16);
    pk.z = (uint32_t)bf16_rne(r[4]) | ((uint32_t)bf16_rne(r[5]) << 16);
    pk.w = (uint32_t)bf16_rne(r[6]) | ((uint32_t)bf16_rne(r[7]) << 16);
    *(uint4*)(Wq + (size_t)gidx * 8) = pk;
}

// ---------- kernel 2: x fp32 -> bf16 ----------
__global__ __launch_bounds__(256) void k_cvt(
        const float* __restrict__ x, unsigned short* __restrict__ Xq) {
    size_t i = ((size_t)blockIdx.x * 256 + threadIdx.x) * 8;
    float4 v0 = *(const float4*)(x + i);
    float4 v1 = *(const float4*)(x + i + 4);
    uint4 pk;
    pk.x = (uint32_t)bf16_rne(v0.x) | ((uint32_t)bf16_rne(v0.y) << 16);
    pk.y = (uint32_t)bf16_rne(v0.z) | ((uint32_t)bf16_rne(v0.w) << 16);
    pk.z = (uint32_t)bf16_rne(v1.x) | ((uint32_t)bf16_rne(v1.y) << 16);
    pk.w = (uint32_t)bf16_rne(v1.z) | ((uint32_t)bf16_rne(v1.w) << 16);
    *(uint4*)(Xq + i) = pk;
}

// ---------- kernel 3: 256x256 GEMM, rotated read-ahead  C = Xq*Wq^T + bias --
// BM=BN=256, BK=64, 8 waves (2Mx4N), LDS 128 KiB (4 static buffers).
// R12: cross-wave-safe read-ahead. PROTOCOL: a tile becomes readable only
// AFTER the barrier that follows the VMW retiring it (VMW is per-wave; the
// barrier publishes all waves' loads). R11 read before that barrier -> NaN.
// Rotation: every QUAD's operands were ds_read >=1 region earlier, and all
// reads occur after their tile's publishing barrier:
//   R1: rd ar03(t)        | Q_D(t-1)       R5: rd ar03(t+1)  | Q_D(t)
//   R2: rd br01,br23(t)   | Q_A(t)         R6: rd br01,23(t+1)| Q_A(t+1)
//   R3: rd ar47(t), stage t+2 B | Q_B(t)   R7: rd ar47(t+1), stage t+3 B | Q_B(t+1)
//   R4: stage t+2 A, VMW(8) | Q_C(t)       R8: stage t+3 A, VMW(8) | Q_C(t+1)
// Publications: t+1 at R4's barrier (read from R5); t+2 at R8's (read R1').
// LGKM0 before each stage = same-wave WAR drain (reads 1 region old, ~free).

#define BARRIER() __builtin_amdgcn_s_barrier()
#define VMW(n)    asm volatile("s_waitcnt vmcnt(" #n ")")
#define LGKM0()   asm volatile("s_waitcnt lgkmcnt(0)")
#define SCHED0()  __builtin_amdgcn_sched_barrier(0)

#define GL16(gp, lp) __builtin_amdgcn_global_load_lds(                        \
    (const __attribute__((address_space(1))) void*)(gp),                      \
    (__attribute__((address_space(3))) void*)(lp), 16, 0, 0)

__global__ __launch_bounds__(512, 2) void k_gemm(
        const unsigned short* __restrict__ A,   // [M_TOK][IN_F] bf16
        const unsigned short* __restrict__ B,   // [OUT_F][IN_F] bf16 (B^T layout)
        const float* __restrict__ bias,
        float* __restrict__ out) {
    __shared__ unsigned short lA0[256 * 64];   // 32 KiB each
    __shared__ unsigned short lA1[256 * 64];
    __shared__ unsigned short lB0[256 * 64];
    __shared__ unsigned short lB1[256 * 64];

    const int tid = threadIdx.x;
    const int l = tid & 63;
    const int w = tid >> 6;            // wave 0..7
    const int wm = w >> 2, wn = w & 3; // 2 x 4 wave grid; wave tile 128x64

    // T1: bijective XCD swizzle. grid 1376 = 8 XCD * (4 row-chunks * 43 cols)
    int lid = blockIdx.x;
    int xcd = lid & 7, j = lid >> 3;   // j in [0,172)
    int bx = j >> 2;                   // col block 0..42
    int by = (xcd << 2) + (j & 3);     // row block 0..31
    const int rowBase = by * 256;
    const int colBase = bx * 256;

    // ---- staging addressing (T2: swizzle on GLOBAL source; LDS linear)
    const int srow = w * 8 + (l >> 3);
    const int scol = ((l & 7) ^ ((l >> 3) & 7)) << 3;   // swizzled element col
    const unsigned short* gA = A + (size_t)(rowBase + srow) * IN_F + scol;
    const unsigned short* gB = B + (size_t)(colBase + srow) * IN_F + scol;
    unsigned short* lA0w = &lA0[w * 8 * 64];
    unsigned short* lA1w = &lA1[w * 8 * 64];
    unsigned short* lB0w = &lB0[w * 8 * 64];
    unsigned short* lB1w = &lB1[w * 8 * 64];

#define STAGEQ_(P, t, q) do {                                                 \
    const unsigned short* _g = (((q) < 2) ? gA : gB) + (size_t)(t) * 64;      \
    unsigned short* _l = (((q) < 2) ? lA##P##w : lB##P##w);                   \
    const int _r = ((q) & 1) * 128;                                           \
    GL16(_g + (size_t)_r * IN_F,        _l + _r * 64);                        \
    GL16(_g + (size_t)(_r + 64) * IN_F, _l + (_r + 64) * 64);                 \
} while (0)

    // ---- fragment reads (swizzled chunk = (kk*4+g) ^ (row&7))
    const int frow = l & 15, g = l >> 4;
    const int cho0 = ((g ^ (frow & 7)) << 4);
    const int cho1 = (((4 + g) ^ (frow & 7)) << 4);
    const char* rowA0 = (const char*)&lA0[(wm * 128 + frow) * 64];
    const char* rowA1 = (const char*)&lA1[(wm * 128 + frow) * 64];
    const char* rowB0 = (const char*)&lB0[(wn * 64 + frow) * 64];
    const char* rowB1 = (const char*)&lB1[(wn * 64 + frow) * 64];
#define LDA_(P, m, kk) (*(const short8*)(rowA##P + (m) * 2048 + ((kk) ? cho1 : cho0)))
#define LDB_(P, n, kk) (*(const short8*)(rowB##P + (n) * 2048 + ((kk) ? cho1 : cho0)))

    f32x4 acc[8][4] = {};
    short8 arA[4][2];   // ar03 of current tile
    short8 arB[4][2];   // ar47 of current tile
    short8 brB[2][2];   // br23 of current tile
    short8 brA0[2][2];  // br01 of buf0 tile
    short8 brA1[2][2];  // br01 of buf1 tile

#define QUADQ(M0, N0, AR, BR) do {                                            \
    __builtin_amdgcn_s_setprio(1);                                            \
    _Pragma("unroll") for (int mm = 0; mm < 4; ++mm)                          \
    _Pragma("unroll") for (int nn = 0; nn < 2; ++nn)                          \
    _Pragma("unroll") for (int kk = 0; kk < 2; ++kk)                          \
        acc[(M0) + mm][(N0) + nn] = __builtin_amdgcn_mfma_f32_16x16x32_bf16(  \
            AR[mm][kk], BR[nn][kk], acc[(M0) + mm][(N0) + nn], 0, 0, 0);      \
    __builtin_amdgcn_s_setprio(0);                                            \
} while (0)

#define RD_A03_(P) do {                                                       \
    _Pragma("unroll") for (int mm = 0; mm < 4; ++mm) {                        \
        arA[mm][0] = LDA_(P, mm, 0); arA[mm][1] = LDA_(P, mm, 1); }           \
} while (0)
#define RD_A47_(P) do {                                                       \
    _Pragma("unroll") for (int mm = 0; mm < 4; ++mm) {                        \
        arB[mm][0] = LDA_(P, 4 + mm, 0); arB[mm][1] = LDA_(P, 4 + mm, 1); }   \
} while (0)
#define RD_BR23_(P) do {                                                      \
    brB[0][0] = LDB_(P, 2, 0); brB[0][1] = LDB_(P, 2, 1);                     \
    brB[1][0] = LDB_(P, 3, 0); brB[1][1] = LDB_(P, 3, 1);                     \
} while (0)
#define RD_B01_(P, BR) do {                                                   \
    BR[0][0] = LDB_(P, 0, 0); BR[0][1] = LDB_(P, 0, 1);                       \
    BR[1][0] = LDB_(P, 1, 0); BR[1][1] = LDB_(P, 1, 1);                       \
} while (0)

    // prologue: stage t0 + t1; VMW(8) retires t0; barrier PUBLISHES t0;
    // then the R1(0) reads (no QUAD -- Q_D(-1) doesn't exist).
    STAGEQ_(0, 0, 0); STAGEQ_(0, 0, 1); STAGEQ_(0, 0, 2); STAGEQ_(0, 0, 3);
    STAGEQ_(1, 1, 2); STAGEQ_(1, 1, 3); STAGEQ_(1, 1, 0); STAGEQ_(1, 1, 1);
    VMW(8); BARRIER();
    SCHED0(); RD_A03_(0);

    // main loop: body = [R2(t)..R8(t), R1(t+2)]; i = 0..30, t = 2i.
    for (int i = 0; i < 31; ++i) {
        int t = 2 * i;
        // R2: rd br01(t),br23(t) | Q_A(t)
        RD_B01_(0, brA0); RD_BR23_(0);
        BARRIER(); QUADQ(0, 0, arA, brA0); BARRIER();
        // R3: rd ar47(t); stage t+2 B-half -> lB0 | Q_B(t)
        LGKM0(); RD_A47_(0);
        STAGEQ_(0, t + 2, 2); STAGEQ_(0, t + 2, 3);
        BARRIER(); QUADQ(0, 2, arA, brB); BARRIER();
        // R4: stage t+2 A-half -> lA0; VMW(8) retires t+1 | Q_C(t)
        LGKM0();
        STAGEQ_(0, t + 2, 0); STAGEQ_(0, t + 2, 1); VMW(8);
        BARRIER(); QUADQ(4, 2, arB, brB); BARRIER();   // publishes t+1
        // R5: rd ar03(t+1) | Q_D(t)
        SCHED0(); RD_A03_(1);
        BARRIER(); QUADQ(4, 0, arB, brA0); BARRIER();
        // R6: rd br01(t+1),br23(t+1) | Q_A(t+1)
        RD_B01_(1, brA1); RD_BR23_(1);
        BARRIER(); QUADQ(0, 0, arA, brA1); BARRIER();
        // R7: rd ar47(t+1); stage t+3 B-half -> lB1 | Q_B(t+1)
        LGKM0(); RD_A47_(1);
        STAGEQ_(1, t + 3, 2); STAGEQ_(1, t + 3, 3);
        BARRIER(); QUADQ(0, 2, arA, brB); BARRIER();
        // R8: stage t+3 A-half -> lA1; VMW(8) retires t+2 | Q_C(t+1)
        LGKM0();
        STAGEQ_(1, t + 3, 0); STAGEQ_(1, t + 3, 1); VMW(8);
        BARRIER(); QUADQ(4, 2, arB, brB); BARRIER();   // publishes t+2
        // R1(next): rd ar03(t+2) | Q_D(t+1)
        SCHED0(); RD_A03_(0);
        BARRIER(); QUADQ(4, 0, arB, brA1); BARRIER();
    }

    // tail: tiles 62 (buf0), 63 (buf1); no staging.
    // entering: arA=ar03(62); 63's 8 loads outstanding.
    RD_B01_(0, brA0); RD_BR23_(0);
    BARRIER(); QUADQ(0, 0, arA, brA0); BARRIER();      // Q_A(62)
    RD_A47_(0);
    BARRIER(); QUADQ(0, 2, arA, brB); BARRIER();       // Q_B(62)
    VMW(0);
    BARRIER(); QUADQ(4, 2, arB, brB); BARRIER();       // Q_C(62); publishes 63
    SCHED0(); RD_A03_(1);
    BARRIER(); QUADQ(4, 0, arB, brA0); BARRIER();      // Q_D(62)
    RD_B01_(1, brA1); RD_BR23_(1);
    BARRIER(); QUADQ(0, 0, arA, brA1); BARRIER();      // Q_A(63)
    RD_A47_(1);
    BARRIER(); QUADQ(0, 2, arA, brB); BARRIER();       // Q_B(63)
    BARRIER(); QUADQ(4, 2, arB, brB); BARRIER();       // Q_C(63)
    QUADQ(4, 0, arB, brA1);                            // Q_D(63)

    // epilogue: C/D layout col = lane&15, row = (lane>>4)*4 + jj
#pragma unroll
    for (int n = 0; n < 4; ++n) {
        int gcol = colBase + wn * 64 + n * 16 + frow;
        float bv = bias[gcol];
#pragma unroll
        for (int m = 0; m < 8; ++m) {
            int grow0 = rowBase + wm * 128 + m * 16 + g * 4;
#pragma unroll
            for (int jj = 0; jj < 4; ++jj)
                out[(size_t)(grow0 + jj) * OUT_F + gcol] = acc[m][n][jj] + bv;
        }
    }
}

// ---------- launch ----------
extern "C" void kernel_launch(void* const* d_in, const int* in_sizes, int n_in,
                              void* d_out, int out_size, void* d_ws, size_t ws_size,
                              hipStream_t stream) {
    const float* x         = (const float*)d_in[0];
    const int*   codes     = (const int*)d_in[1];
    const float* codebooks = (const float*)d_in[2];
    const float* scales    = (const float*)d_in[3];
    const float* bias      = (const float*)d_in[4];
    float* out = (float*)d_out;

    // workspace: Wq bf16 [OUT_F][IN_F], Xq bf16 [M_TOK][IN_F] = 157,286,400 B
    unsigned short* Wq = (unsigned short*)d_ws;
    unsigned short* Xq = (unsigned short*)((char*)d_ws + (size_t)OUT_F * IN_F * 2);

    k_dequant<<<NGRP / 256, 256, 0, stream>>>(codes, codebooks, scales, Wq);
    k_cvt<<<(M_TOK * IN_F / 8) / 256, 256, 0, stream>>>(x, Xq);
    // grid: (8192/256) * (11008/256) = 32 * 43 = 1376 blocks, 512 threads
    k_gemm<<<1376, 512, 0, stream>>>(Xq, Wq, bias, out);
}

// Round 13
// 766.252 us; speedup vs baseline: 1.1392x; 1.1392x over previous
//
#include <hip/hip_runtime.h>
#include <hip/hip_bf16.h>
#include <stdint.h>

// Problem constants (QuantizedLinear_15985868276124)
#define IN_F   4096
#define OUT_F  11008
#define M_TOK  8192                  // 4 * 2048 tokens
#define NGRP   (OUT_F * (IN_F / 8)) // 5,636,096 groups of 8 weights

typedef __attribute__((ext_vector_type(8))) short short8;
typedef __attribute__((ext_vector_type(4))) float f32x4;

// ---------- helpers ----------

__device__ __forceinline__ unsigned short bf16_rne(float f) {
    union { float f; uint32_t u; } v; v.f = f;
    uint32_t r = v.u + 0x7FFFu + ((v.u >> 16) & 1u); // round-to-nearest-even
    return (unsigned short)(r >> 16);
}

// ---------- kernel 1: dequantize W -> bf16 [OUT_F][IN_F] ----------
__global__ __launch_bounds__(256) void k_dequant(
        const int* __restrict__ codes,
        const float* __restrict__ codebooks,
        const float* __restrict__ scales,
        unsigned short* __restrict__ Wq) {
    __shared__ float cb[4096]; // [2][256][8]
    int tid = threadIdx.x;
    const float4* cbg = (const float4*)codebooks;
    float4* cbl = (float4*)cb;
#pragma unroll
    for (int i = 0; i < 4; ++i) cbl[tid + i * 256] = cbg[tid + i * 256];
    __syncthreads();

    int gidx = blockIdx.x * 256 + tid;      // group index in [0, NGRP)
    int o = gidx >> 9;                      // / 512
    float s = scales[o];
    int2 c = ((const int2*)codes)[gidx];

    const float4* e0 = (const float4*)&cb[c.x * 8];
    const float4* e1 = (const float4*)&cb[2048 + c.y * 8];
    float4 a0 = e0[0], a1 = e0[1];
    float4 b0 = e1[0], b1 = e1[1];

    float r[8];
    r[0] = (a0.x + b0.x) * s; r[1] = (a0.y + b0.y) * s;
    r[2] = (a0.z + b0.z) * s; r[3] = (a0.w + b0.w) * s;
    r[4] = (a1.x + b1.x) * s; r[5] = (a1.y + b1.y) * s;
    r[6] = (a1.z + b1.z) * s; r[7] = (a1.w + b1.w) * s;

    uint4 pk;
    pk.x = (uint32_t)bf16_rne(r[0]) | ((uint32_t)bf16_rne(r[1]) << 16);
    pk.y = (uint32_t)bf16_rne(r[2]) | ((uint32_t)bf16_rne(r[3]) << 16);
    pk.z = (uint32_t)bf16_rne(r[4]) | ((uint32_t)bf16_rne(r[5]) << 16);
    pk.w = (uint32_t)bf16_rne(r[6]) | ((uint32_t)bf16_rne(r[7]) << 16);
    *(uint4*)(Wq + (size_t)gidx * 8) = pk;
}

// ---------- kernel 2: x fp32 -> bf16 ----------
__global__ __launch_bounds__(256) void k_cvt(
        const float* __restrict__ x, unsigned short* __restrict__ Xq) {
    size_t i = ((size_t)blockIdx.x * 256 + threadIdx.x) * 8;
    float4 v0 = *(const float4*)(x + i);
    float4 v1 = *(const float4*)(x + i + 4);
    uint4 pk;
    pk.x = (uint32_t)bf16_rne(v0.x) | ((uint32_t)bf16_rne(v0.y) << 16);
    pk.y = (uint32_t)bf16_rne(v0.z) | ((uint32_t)bf16_rne(v0.w) << 16);
    pk.z = (uint32_t)bf16_rne(v1.x) | ((uint32_t)bf16_rne(v1.y) << 16);
    pk.w = (uint32_t)bf16_rne(v1.z) | ((uint32_t)bf16_rne(v1.w) << 16);
    *(uint4*)(Xq + i) = pk;
}

// ---------- kernel 3: 256x256 GEMM, single-barrier phases ----------
// BM=BN=256, BK=64, 8 waves (2Mx4N), LDS 128 KiB (4 static buffers).
// R13 = R10 (best known, 770us) with ONE barrier per phase instead of two:
//   phase = { reads/stage ; QUAD ; BARRIER }    (4 barriers/K-tile, was 8)
// WAR protocol preserved: each phase's ds_reads are consumed by its own
// QUAD (compiler counted lgkmcnt) => drained before the phase's closing
// barrier => later-phase staging cannot clobber unread rows. Publication
// unchanged: VMW(8) precedes D's closing barrier; t+1 read after it.
// Hypothesis under test: 8-wave barrier sync jitter is the unexplained
// ~1500 cyc/K-tile vs m201's rate (my accounted work: MFMA 620 + LDS ~577).

#define BARRIER() __builtin_amdgcn_s_barrier()
#define VMW(n)    asm volatile("s_waitcnt vmcnt(" #n ")")

#define GL16(gp, lp) __builtin_amdgcn_global_load_lds(                        \
    (const __attribute__((address_space(1))) void*)(gp),                      \
    (__attribute__((address_space(3))) void*)(lp), 16, 0, 0)

__global__ __launch_bounds__(512, 2) void k_gemm(
        const unsigned short* __restrict__ A,   // [M_TOK][IN_F] bf16
        const unsigned short* __restrict__ B,   // [OUT_F][IN_F] bf16 (B^T layout)
        const float* __restrict__ bias,
        float* __restrict__ out) {
    __shared__ unsigned short lA0[256 * 64];   // 32 KiB each
    __shared__ unsigned short lA1[256 * 64];
    __shared__ unsigned short lB0[256 * 64];
    __shared__ unsigned short lB1[256 * 64];

    const int tid = threadIdx.x;
    const int l = tid & 63;
    const int w = tid >> 6;            // wave 0..7
    const int wm = w >> 2, wn = w & 3; // 2 x 4 wave grid; wave tile 128x64

    // T1: bijective XCD swizzle. grid 1376 = 8 XCD * (4 row-chunks * 43 cols)
    int lid = blockIdx.x;
    int xcd = lid & 7, j = lid >> 3;   // j in [0,172)
    int bx = j >> 2;                   // col block 0..42
    int by = (xcd << 2) + (j & 3);     // row block 0..31
    const int rowBase = by * 256;
    const int colBase = bx * 256;

    // ---- staging addressing (T2: swizzle on GLOBAL source; LDS linear)
    const int srow = w * 8 + (l >> 3);
    const int scol = ((l & 7) ^ ((l >> 3) & 7)) << 3;   // swizzled element col
    const unsigned short* gA = A + (size_t)(rowBase + srow) * IN_F + scol;
    const unsigned short* gB = B + (size_t)(colBase + srow) * IN_F + scol;
    unsigned short* lA0w = &lA0[w * 8 * 64];
    unsigned short* lA1w = &lA1[w * 8 * 64];
    unsigned short* lB0w = &lB0[w * 8 * 64];
    unsigned short* lB1w = &lB1[w * 8 * 64];

#define STAGEQ_(P, t, q) do {                                                 \
    const unsigned short* _g = (((q) < 2) ? gA : gB) + (size_t)(t) * 64;      \
    unsigned short* _l = (((q) < 2) ? lA##P##w : lB##P##w);                   \
    const int _r = ((q) & 1) * 128;                                           \
    GL16(_g + (size_t)_r * IN_F,        _l + _r * 64);                        \
    GL16(_g + (size_t)(_r + 64) * IN_F, _l + (_r + 64) * 64);                 \
} while (0)

    // ---- fragment reads (swizzled chunk = (kk*4+g) ^ (row&7))
    const int frow = l & 15, g = l >> 4;
    const int cho0 = ((g ^ (frow & 7)) << 4);
    const int cho1 = (((4 + g) ^ (frow & 7)) << 4);
    const char* rowA0 = (const char*)&lA0[(wm * 128 + frow) * 64];
    const char* rowA1 = (const char*)&lA1[(wm * 128 + frow) * 64];
    const char* rowB0 = (const char*)&lB0[(wn * 64 + frow) * 64];
    const char* rowB1 = (const char*)&lB1[(wn * 64 + frow) * 64];
#define LDA_(P, m, kk) (*(const short8*)(rowA##P + (m) * 2048 + ((kk) ? cho1 : cho0)))
#define LDB_(P, n, kk) (*(const short8*)(rowB##P + (n) * 2048 + ((kk) ? cho1 : cho0)))

    f32x4 acc[8][4] = {};
    short8 ar[4][2], br[4][2];

#define QUAD(M0, N0) do {                                                     \
    __builtin_amdgcn_s_setprio(1);                                            \
    _Pragma("unroll") for (int mm = 0; mm < 4; ++mm)                          \
    _Pragma("unroll") for (int nn = 0; nn < 2; ++nn)                          \
    _Pragma("unroll") for (int kk = 0; kk < 2; ++kk)                          \
        acc[(M0) + mm][(N0) + nn] = __builtin_amdgcn_mfma_f32_16x16x32_bf16(  \
            ar[mm][kk], br[(N0) + nn][kk], acc[(M0) + mm][(N0) + nn], 0, 0, 0);\
    __builtin_amdgcn_s_setprio(0);                                            \
} while (0)

#define RD_A03_B01(P) do {                                                    \
    _Pragma("unroll") for (int mm = 0; mm < 4; ++mm) {                        \
        ar[mm][0] = LDA_(P, mm, 0); ar[mm][1] = LDA_(P, mm, 1); }             \
    br[0][0] = LDB_(P, 0, 0); br[0][1] = LDB_(P, 0, 1);                       \
    br[1][0] = LDB_(P, 1, 0); br[1][1] = LDB_(P, 1, 1);                       \
} while (0)
#define RD_B23(P) do {                                                        \
    br[2][0] = LDB_(P, 2, 0); br[2][1] = LDB_(P, 2, 1);                       \
    br[3][0] = LDB_(P, 3, 0); br[3][1] = LDB_(P, 3, 1);                       \
} while (0)
#define RD_A47(P) do {                                                        \
    _Pragma("unroll") for (int mm = 0; mm < 4; ++mm) {                        \
        ar[mm][0] = LDA_(P, 4 + mm, 0); ar[mm][1] = LDA_(P, 4 + mm, 1); }     \
} while (0)

    // prologue: stage tile0 fully (buf0), then tile1 in C/D order;
    // VMW(8) retires t0's 8; barrier publishes tile0.
    STAGEQ_(0, 0, 0); STAGEQ_(0, 0, 1); STAGEQ_(0, 0, 2); STAGEQ_(0, 0, 3);
    STAGEQ_(1, 1, 2); STAGEQ_(1, 1, 3); STAGEQ_(1, 1, 0); STAGEQ_(1, 1, 1);
    VMW(8); BARRIER();

    // main loop: 2 K-tiles/iter (t=2i in buf0, t+1 in buf1); i = 0..30.
    // Stagger (from R10): C stages next-next tile's B-half, D its A-half +
    // VMW(8) retiring the tile read next phase (issued >=4 phases earlier).
    for (int i = 0; i < 31; ++i) {
        int t = 2 * i;
        // A0
        RD_A03_B01(0);
        QUAD(0, 0); BARRIER();
        // B0
        RD_B23(0);
        QUAD(0, 2); BARRIER();
        // C0: stage B-half of t+2 -> buf0
        RD_A47(0); STAGEQ_(0, t + 2, 2); STAGEQ_(0, t + 2, 3);
        QUAD(4, 2); BARRIER();
        // D0: stage A-half of t+2; VMW(8) retires t+1; barrier publishes it
        STAGEQ_(0, t + 2, 0); STAGEQ_(0, t + 2, 1); VMW(8);
        QUAD(4, 0); BARRIER();
        // A1
        RD_A03_B01(1);
        QUAD(0, 0); BARRIER();
        // B1
        RD_B23(1);
        QUAD(0, 2); BARRIER();
        // C1: stage B-half of t+3 -> buf1
        RD_A47(1); STAGEQ_(1, t + 3, 2); STAGEQ_(1, t + 3, 3);
        QUAD(4, 2); BARRIER();
        // D1: stage A-half of t+3; VMW(8) retires t+2; barrier publishes it
        STAGEQ_(1, t + 3, 0); STAGEQ_(1, t + 3, 1); VMW(8);
        QUAD(4, 0); BARRIER();
    }

    // peeled last pair (tiles 62 in buf0, 63 in buf1); no new staging
    RD_A03_B01(0);
    QUAD(0, 0); BARRIER();
    RD_B23(0);
    QUAD(0, 2); BARRIER();
    RD_A47(0);
    QUAD(4, 2); BARRIER();
    VMW(0);                                  // tile 63 complete; barrier publishes
    QUAD(4, 0); BARRIER();
    RD_A03_B01(1);
    QUAD(0, 0); BARRIER();
    RD_B23(1);
    QUAD(0, 2); BARRIER();
    RD_A47(1);
    QUAD(4, 2); BARRIER();
    QUAD(4, 0);

    // epilogue: C/D layout col = lane&15, row = (lane>>4)*4 + jj
#pragma unroll
    for (int n = 0; n < 4; ++n) {
        int gcol = colBase + wn * 64 + n * 16 + frow;
        float bv = bias[gcol];
#pragma unroll
        for (int m = 0; m < 8; ++m) {
            int grow0 = rowBase + wm * 128 + m * 16 + g * 4;
#pragma unroll
            for (int jj = 0; jj < 4; ++jj)
                out[(size_t)(grow0 + jj) * OUT_F + gcol] = acc[m][n][jj] + bv;
        }
    }
}

// ---------- launch ----------
extern "C" void kernel_launch(void* const* d_in, const int* in_sizes, int n_in,
                              void* d_out, int out_size, void* d_ws, size_t ws_size,
                              hipStream_t stream) {
    const float* x         = (const float*)d_in[0];
    const int*   codes     = (const int*)d_in[1];
    const float* codebooks = (const float*)d_in[2];
    const float* scales    = (const float*)d_in[3];
    const float* bias      = (const float*)d_in[4];
    float* out = (float*)d_out;

    // workspace: Wq bf16 [OUT_F][IN_F], Xq bf16 [M_TOK][IN_F] = 157,286,400 B
    unsigned short* Wq = (unsigned short*)d_ws;
    unsigned short* Xq = (unsigned short*)((char*)d_ws + (size_t)OUT_F * IN_F * 2);

    k_dequant<<<NGRP / 256, 256, 0, stream>>>(codes, codebooks, scales, Wq);
    k_cvt<<<(M_TOK * IN_F / 8) / 256, 256, 0, stream>>>(x, Xq);
    // grid: (8192/256) * (11008/256) = 32 * 43 = 1376 blocks, 512 threads
    k_gemm<<<1376, 512, 0, stream>>>(Xq, Wq, bias, out);
}

// Round 14
// 465.952 us; speedup vs baseline: 1.8735x; 1.6445x over previous
//
#include <hip/hip_runtime.h>
#include <hip/hip_bf16.h>
#include <stdint.h>

// Problem constants (QuantizedLinear_15985868276124)
#define IN_F   4096                 // bytes per i8 row == elements
#define OUT_F  11008
#define M_TOK  8192

typedef __attribute__((ext_vector_type(4))) int   int32x4;
typedef __attribute__((ext_vector_type(4))) float f32x4;

// ---------- block row-max reduction helper ----------
__device__ __forceinline__ float block_rowmax(float m, float* red, int t) {
    red[t] = m; __syncthreads();
    for (int s = 128; s > 0; s >>= 1) {
        if (t < s) red[t] = fmaxf(red[t], red[t + s]);
        __syncthreads();
    }
    float r = red[0]; __syncthreads();
    return fmaxf(r, 1e-8f);
}

// ---------- kernel 1: quantize x rows -> i8 + sx ----------
// one block per token row; 256 thr x 16 elems
__global__ __launch_bounds__(256) void k_qx(
        const float* __restrict__ x, signed char* __restrict__ Xq,
        float* __restrict__ sx) {
    __shared__ float red[256];
    int r = blockIdx.x, t = threadIdx.x;
    const float4* xr = (const float4*)(x + (size_t)r * IN_F) + t * 4;
    float4 v0 = xr[0], v1 = xr[1], v2 = xr[2], v3 = xr[3];
    float m = 0.f;
#define MX4(v) m = fmaxf(m, fmaxf(fmaxf(fabsf(v.x), fabsf(v.y)), fmaxf(fabsf(v.z), fabsf(v.w))))
    MX4(v0); MX4(v1); MX4(v2); MX4(v3);
    float rm = block_rowmax(m, red, t);
    if (t == 0) sx[r] = rm / 127.f;
    float inv = 127.f / rm;
    union { signed char c[16]; uint4 u; } pk;
#define Q4(v, o) pk.c[o] = (signed char)__float2int_rn(v.x * inv);            \
                 pk.c[o+1] = (signed char)__float2int_rn(v.y * inv);          \
                 pk.c[o+2] = (signed char)__float2int_rn(v.z * inv);          \
                 pk.c[o+3] = (signed char)__float2int_rn(v.w * inv)
    Q4(v0, 0); Q4(v1, 4); Q4(v2, 8); Q4(v3, 12);
    *(uint4*)(Xq + (size_t)r * IN_F + t * 16) = pk.u;
}

// ---------- kernel 2: dequant + quantize W rows -> i8 + sw ----------
// one block per out row; codes[o][512][2], codebooks [2][256][1][8] f32
__global__ __launch_bounds__(256) void k_qw(
        const int* __restrict__ codes,
        const float* __restrict__ codebooks,
        const float* __restrict__ scales,
        signed char* __restrict__ Wq, float* __restrict__ sw) {
    __shared__ float cb[4096];  // [2][256][8]
    __shared__ float red[256];
    int o = blockIdx.x, t = threadIdx.x;
    {
        const float4* cbg = (const float4*)codebooks;
        float4* cbl = (float4*)cb;
#pragma unroll
        for (int i = 0; i < 4; ++i) cbl[t + i * 256] = cbg[t + i * 256];
    }
    __syncthreads();
    // thread t: groups 2t, 2t+1 -> 16 e-values (w = s_o * e)
    const int2* cp = (const int2*)codes + (size_t)o * 512 + t * 2;
    int2 c0 = cp[0], c1 = cp[1];
    float e[16]; float m = 0.f;
#pragma unroll
    for (int j = 0; j < 8; ++j) {
        e[j]     = cb[c0.x * 8 + j] + cb[2048 + c0.y * 8 + j];
        e[8 + j] = cb[c1.x * 8 + j] + cb[2048 + c1.y * 8 + j];
    }
#pragma unroll
    for (int j = 0; j < 16; ++j) m = fmaxf(m, fabsf(e[j]));
    float rm = block_rowmax(m, red, t);
    if (t == 0) sw[o] = scales[o] * rm / 127.f;
    float inv = 127.f / rm;
    union { signed char c[16]; uint4 u; } pk;
#pragma unroll
    for (int j = 0; j < 16; ++j) pk.c[j] = (signed char)__float2int_rn(e[j] * inv);
    *(uint4*)(Wq + (size_t)o * IN_F + t * 16) = pk.u;
}

// ---------- kernel 3: 256x256 i8 GEMM (R13 structure, K-tile=128B) --------
// Byte geometry identical to R13's bf16: 128B rows, 8x16B chunks, same XOR
// swizzle, 8 gload_lds/tile, same vmcnt ledger. mfma_i32_16x16x64_i8 keeps
// the 16x16 C/D layout. 32 K-tiles (4096B / 128B). Per-K: MFMA floor and
// LDS bytes halve vs bf16.

#define BARRIER() __builtin_amdgcn_s_barrier()
#define VMW(n)    asm volatile("s_waitcnt vmcnt(" #n ")")

#define GL16(gp, lp) __builtin_amdgcn_global_load_lds(                        \
    (const __attribute__((address_space(1))) void*)(gp),                      \
    (__attribute__((address_space(3))) void*)(lp), 16, 0, 0)

__global__ __launch_bounds__(512, 2) void k_gemm(
        const signed char* __restrict__ A,   // [M_TOK][IN_F] i8
        const signed char* __restrict__ B,   // [OUT_F][IN_F] i8 (B^T layout)
        const float* __restrict__ sx,        // [M_TOK]
        const float* __restrict__ sw,        // [OUT_F]
        const float* __restrict__ bias,
        float* __restrict__ out) {
    __shared__ signed char lA0[256 * 128];   // 32 KiB each
    __shared__ signed char lA1[256 * 128];
    __shared__ signed char lB0[256 * 128];
    __shared__ signed char lB1[256 * 128];

    const int tid = threadIdx.x;
    const int l = tid & 63;
    const int w = tid >> 6;            // wave 0..7
    const int wm = w >> 2, wn = w & 3; // 2 x 4 wave grid; wave tile 128x64

    // T1: bijective XCD swizzle. grid 1376 = 8 XCD * (4 row-chunks * 43 cols)
    int lid = blockIdx.x;
    int xcd = lid & 7, j = lid >> 3;
    int bx = j >> 2;                   // col block 0..42
    int by = (xcd << 2) + (j & 3);     // row block 0..31
    const int rowBase = by * 256;
    const int colBase = bx * 256;

    // ---- staging addressing (swizzle on GLOBAL source; LDS linear)
    // row = base + w*8 + (l>>3); byte chunk = (l&7) ^ (row&7)
    const int srow = w * 8 + (l >> 3);
    const int scol = ((l & 7) ^ ((l >> 3) & 7)) << 4;   // byte offset in row
    const signed char* gA = A + (size_t)(rowBase + srow) * IN_F + scol;
    const signed char* gB = B + (size_t)(colBase + srow) * IN_F + scol;
    signed char* lA0w = &lA0[w * 8 * 128];
    signed char* lA1w = &lA1[w * 8 * 128];
    signed char* lB0w = &lB0[w * 8 * 128];
    signed char* lB1w = &lB1[w * 8 * 128];

    // stage one quarter of K-tile t (t in units of 128B): q0/q1 = A rows
    // {0-127,128-255}; q2/q3 = B same
#define STAGEQ_(P, t, q) do {                                                 \
    const signed char* _g = (((q) < 2) ? gA : gB) + (size_t)(t) * 128;        \
    signed char* _l = (((q) < 2) ? lA##P##w : lB##P##w);                      \
    const int _r = ((q) & 1) * 128;                                           \
    GL16(_g + (size_t)_r * IN_F,        _l + _r * 128);                       \
    GL16(_g + (size_t)(_r + 64) * IN_F, _l + (_r + 64) * 128);                \
} while (0)

    // ---- fragment reads: lane row = frag*16 + (l&15); 16B at chunk
    // (kk*4 + (l>>4)) ^ (row&7)  [kk = K-half of the 128B tile]
    const int frow = l & 15, g = l >> 4;
    const int cho0 = ((g ^ (frow & 7)) << 4);
    const int cho1 = (((4 + g) ^ (frow & 7)) << 4);
    const char* rowA0 = (const char*)&lA0[(wm * 128 + frow) * 128];
    const char* rowA1 = (const char*)&lA1[(wm * 128 + frow) * 128];
    const char* rowB0 = (const char*)&lB0[(wn * 64 + frow) * 128];
    const char* rowB1 = (const char*)&lB1[(wn * 64 + frow) * 128];
#define LDA_(P, m, kk) (*(const int32x4*)(rowA##P + (m) * 2048 + ((kk) ? cho1 : cho0)))
#define LDB_(P, n, kk) (*(const int32x4*)(rowB##P + (n) * 2048 + ((kk) ? cho1 : cho0)))

    int32x4 acc[8][4] = {};
    int32x4 ar[4][2], br[4][2];

#define QUAD(M0, N0) do {                                                     \
    __builtin_amdgcn_s_setprio(1);                                            \
    _Pragma("unroll") for (int mm = 0; mm < 4; ++mm)                          \
    _Pragma("unroll") for (int nn = 0; nn < 2; ++nn)                          \
    _Pragma("unroll") for (int kk = 0; kk < 2; ++kk)                          \
        acc[(M0) + mm][(N0) + nn] = __builtin_amdgcn_mfma_i32_16x16x64_i8(    \
            ar[mm][kk], br[(N0) + nn][kk], acc[(M0) + mm][(N0) + nn], 0, 0, 0);\
    __builtin_amdgcn_s_setprio(0);                                            \
} while (0)

#define RD_A03_B01(P) do {                                                    \
    _Pragma("unroll") for (int mm = 0; mm < 4; ++mm) {                        \
        ar[mm][0] = LDA_(P, mm, 0); ar[mm][1] = LDA_(P, mm, 1); }             \
    br[0][0] = LDB_(P, 0, 0); br[0][1] = LDB_(P, 0, 1);                       \
    br[1][0] = LDB_(P, 1, 0); br[1][1] = LDB_(P, 1, 1);                       \
} while (0)
#define RD_B23(P) do {                                                        \
    br[2][0] = LDB_(P, 2, 0); br[2][1] = LDB_(P, 2, 1);                       \
    br[3][0] = LDB_(P, 3, 0); br[3][1] = LDB_(P, 3, 1);                       \
} while (0)
#define RD_A47(P) do {                                                        \
    _Pragma("unroll") for (int mm = 0; mm < 4; ++mm) {                        \
        ar[mm][0] = LDA_(P, 4 + mm, 0); ar[mm][1] = LDA_(P, 4 + mm, 1); }     \
} while (0)

    // prologue: stage tile0 (buf0) + tile1 (buf1, C/D order); VMW(8) -> t0 in
    STAGEQ_(0, 0, 0); STAGEQ_(0, 0, 1); STAGEQ_(0, 0, 2); STAGEQ_(0, 0, 3);
    STAGEQ_(1, 1, 2); STAGEQ_(1, 1, 3); STAGEQ_(1, 1, 0); STAGEQ_(1, 1, 1);
    VMW(8); BARRIER();

    // main loop: 2 K-tiles/iter (t=2i buf0, t+1 buf1); i=0..14 (tiles 0..31)
    for (int i = 0; i < 15; ++i) {
        int t = 2 * i;
        // A0
        RD_A03_B01(0);
        QUAD(0, 0); BARRIER();
        // B0
        RD_B23(0);
        QUAD(0, 2); BARRIER();
        // C0: stage B-half of t+2 -> buf0
        RD_A47(0); STAGEQ_(0, t + 2, 2); STAGEQ_(0, t + 2, 3);
        QUAD(4, 2); BARRIER();
        // D0: stage A-half of t+2; VMW(8) retires t+1; barrier publishes it
        STAGEQ_(0, t + 2, 0); STAGEQ_(0, t + 2, 1); VMW(8);
        QUAD(4, 0); BARRIER();
        // A1
        RD_A03_B01(1);
        QUAD(0, 0); BARRIER();
        // B1
        RD_B23(1);
        QUAD(0, 2); BARRIER();
        // C1: stage B-half of t+3 -> buf1
        RD_A47(1); STAGEQ_(1, t + 3, 2); STAGEQ_(1, t + 3, 3);
        QUAD(4, 2); BARRIER();
        // D1: stage A-half of t+3; VMW(8) retires t+2; barrier publishes it
        STAGEQ_(1, t + 3, 0); STAGEQ_(1, t + 3, 1); VMW(8);
        QUAD(4, 0); BARRIER();
    }

    // peeled last pair (tiles 30 buf0, 31 buf1); no new staging
    RD_A03_B01(0);
    QUAD(0, 0); BARRIER();
    RD_B23(0);
    QUAD(0, 2); BARRIER();
    RD_A47(0);
    QUAD(4, 2); BARRIER();
    VMW(0);                                  // tile 31 complete
    QUAD(4, 0); BARRIER();
    RD_A03_B01(1);
    QUAD(0, 0); BARRIER();
    RD_B23(1);
    QUAD(0, 2); BARRIER();
    RD_A47(1);
    QUAD(4, 2); BARRIER();
    QUAD(4, 0);

    // epilogue: C/D layout col = lane&15, row = (lane>>4)*4 + jj
    // out = sx[row]*sw[col]*acc + bias[col]
#pragma unroll
    for (int n = 0; n < 4; ++n) {
        int gcol = colBase + wn * 64 + n * 16 + frow;
        float swv = sw[gcol];
        float bv = bias[gcol];
#pragma unroll
        for (int m = 0; m < 8; ++m) {
            int grow0 = rowBase + wm * 128 + m * 16 + g * 4;
            float4 sx4 = *(const float4*)&sx[grow0];
            out[(size_t)(grow0 + 0) * OUT_F + gcol] = (float)acc[m][n][0] * sx4.x * swv + bv;
            out[(size_t)(grow0 + 1) * OUT_F + gcol] = (float)acc[m][n][1] * sx4.y * swv + bv;
            out[(size_t)(grow0 + 2) * OUT_F + gcol] = (float)acc[m][n][2] * sx4.z * swv + bv;
            out[(size_t)(grow0 + 3) * OUT_F + gcol] = (float)acc[m][n][3] * sx4.w * swv + bv;
        }
    }
}

// ---------- launch ----------
extern "C" void kernel_launch(void* const* d_in, const int* in_sizes, int n_in,
                              void* d_out, int out_size, void* d_ws, size_t ws_size,
                              hipStream_t stream) {
    const float* x         = (const float*)d_in[0];
    const int*   codes     = (const int*)d_in[1];
    const float* codebooks = (const float*)d_in[2];
    const float* scales    = (const float*)d_in[3];
    const float* bias      = (const float*)d_in[4];
    float* out = (float*)d_out;

    // workspace: Wq i8 [OUT_F][IN_F] (45,088,768) ; Xq i8 [M_TOK][IN_F]
    // (33,554,432) ; sx f32 [M_TOK] ; sw f32 [OUT_F]   (total ~78.7 MB)
    signed char* Wq = (signed char*)d_ws;
    signed char* Xq = Wq + (size_t)OUT_F * IN_F;
    float* sx = (float*)(Xq + (size_t)M_TOK * IN_F);
    float* sw = sx + M_TOK;

    k_qx<<<M_TOK, 256, 0, stream>>>(x, Xq, sx);
    k_qw<<<OUT_F, 256, 0, stream>>>(codes, codebooks, scales, Wq, sw);
    // grid: (8192/256) * (11008/256) = 32 * 43 = 1376 blocks, 512 threads
    k_gemm<<<1376, 512, 0, stream>>>(Xq, Wq, sx, sw, bias, out);
}